// Round 5
// baseline (760.301 us; speedup 1.0000x reference)
//
#include <hip/hip_runtime.h>
#include <math.h>

// Problem constants
#define BATCH 2
#define SEQ   2048
#define DIM   2048
#define NH    16
#define HD    128
#define EPS   1e-6f

typedef __bf16 bf16x8 __attribute__((ext_vector_type(8)));
typedef float  f32x4  __attribute__((ext_vector_type(4)));

// bf16 round-to-nearest-even split helpers
__device__ __forceinline__ unsigned short f2bf(float f) {
  union { float f; unsigned u; } v; v.f = f;
  unsigned r = v.u + 0x7FFFu + ((v.u >> 16) & 1u);
  return (unsigned short)(r >> 16);
}
__device__ __forceinline__ float bf2f(unsigned short h) {
  union { unsigned u; float f; } v; v.u = ((unsigned)h) << 16;
  return v.f;
}

// ---------------------------------------------------------------------------
// split fp32 -> (hi, lo) bf16
// ---------------------------------------------------------------------------
__global__ __launch_bounds__(256) void split_bf16(
    const float* __restrict__ in, unsigned short* __restrict__ hi,
    unsigned short* __restrict__ lo) {
  int i = blockIdx.x * 256 + threadIdx.x;
  float4 v = ((const float4*)in)[i];
  ushort4 h, l;
  h.x = f2bf(v.x); l.x = f2bf(v.x - bf2f(h.x));
  h.y = f2bf(v.y); l.y = f2bf(v.y - bf2f(h.y));
  h.z = f2bf(v.z); l.z = f2bf(v.z - bf2f(h.z));
  h.w = f2bf(v.w); l.w = f2bf(v.w - bf2f(h.w));
  ((ushort4*)hi)[i] = h;
  ((ushort4*)lo)[i] = l;
}

// ---------------------------------------------------------------------------
// Split-bf16 MFMA GEMM with PAIRED-ROW XOR SWIZZLED LDS tiles.
// Tile [128 rows][32 cols bf16]; 16B granule (row, c), c in 0..3 stored at:
//   chunk(row>>4)*1024B + ((row>>1)&7)*128B + (((row&1)*4+c) ^ ((row>>1)&7))*16B
// -> every 8-consecutive-lane group of a ds_read_b128 hits slots {0..7}
//    exactly once: conflict-free (old layout was 4-way conflicted).
// Staging stays lane-contiguous (global_load_lds HW requirement); the swizzle
// is realized by permuting WHICH global granule each lane fetches.
// ---------------------------------------------------------------------------
#define BM 128
#define BN 128
#define BK 32

__global__ __launch_bounds__(256) void gemm_split(
    const unsigned short* __restrict__ Ahg, const unsigned short* __restrict__ Alg,
    const unsigned short* __restrict__ Bhg, const unsigned short* __restrict__ Blg,
    float* __restrict__ C, int M, int N, int K) {
  __shared__ __align__(16) unsigned short Ah[BM * BK];
  __shared__ __align__(16) unsigned short Al[BM * BK];
  __shared__ __align__(16) unsigned short Bh[BM * BK];
  __shared__ __align__(16) unsigned short Bl[BM * BK];

  const int t = threadIdx.x;
  const int w = t >> 6, lane = t & 63;
  const int bm = blockIdx.y * BM, bn = blockIdx.x * BN;
  const int wr = (w >> 1) * 64, wc = (w & 1) * 64;
  const int r16 = lane & 15, kg = lane >> 4;

  // staging: lane's (row-in-chunk, col) for the swizzled layout
  const int srp = lane >> 3, ssl = lane & 7, sg = ssl ^ srp;
  const int rowc = srp * 2 + (sg >> 2), colo = (sg & 3) << 3;

  const unsigned short* gsrc;
  unsigned short* lbase;
  if (w == 0)      { gsrc = Ahg + (size_t)bm * K; lbase = Ah; }
  else if (w == 1) { gsrc = Alg + (size_t)bm * K; lbase = Al; }
  else if (w == 2) { gsrc = Bhg + (size_t)bn * K; lbase = Bh; }
  else             { gsrc = Blg + (size_t)bn * K; lbase = Bl; }
  const unsigned short* gl = gsrc + (size_t)rowc * K + colo;

  // fragment read: per-lane constant within-chunk offset (shorts)
  const int rp2 = r16 >> 1;
  const int sfr = (((r16 & 1) << 2) + kg) ^ rp2;
  const int fro = rp2 * 64 + sfr * 8;
  const int aco = (wr >> 4) * 512 + fro;   // + i*512 per fragment
  const int bco = (wc >> 4) * 512 + fro;

  f32x4 acc[4][4] = {};

  for (int k0 = 0; k0 < K; k0 += BK) {
    __syncthreads();
    #pragma unroll
    for (int p = 0; p < 8; ++p) {
      const unsigned short* ga = gl + (size_t)(p * 16) * K + k0;
      __builtin_amdgcn_global_load_lds(
          (const __attribute__((address_space(1))) unsigned int*)ga,
          (__attribute__((address_space(3))) unsigned int*)(lbase + p * 512),
          16, 0, 0);
    }
    __syncthreads();

    bf16x8 ah[4], al[4], bh[4], bl[4];
    #pragma unroll
    for (int i = 0; i < 4; ++i) {
      ah[i] = *(const bf16x8*)(Ah + aco + i * 512);
      al[i] = *(const bf16x8*)(Al + aco + i * 512);
      bh[i] = *(const bf16x8*)(Bh + bco + i * 512);
      bl[i] = *(const bf16x8*)(Bl + bco + i * 512);
    }
    #pragma unroll
    for (int i = 0; i < 4; ++i)
      #pragma unroll
      for (int j = 0; j < 4; ++j)
        acc[i][j] = __builtin_amdgcn_mfma_f32_16x16x32_bf16(ah[i], bh[j], acc[i][j], 0, 0, 0);
    #pragma unroll
    for (int i = 0; i < 4; ++i)
      #pragma unroll
      for (int j = 0; j < 4; ++j)
        acc[i][j] = __builtin_amdgcn_mfma_f32_16x16x32_bf16(ah[i], bl[j], acc[i][j], 0, 0, 0);
    #pragma unroll
    for (int i = 0; i < 4; ++i)
      #pragma unroll
      for (int j = 0; j < 4; ++j)
        acc[i][j] = __builtin_amdgcn_mfma_f32_16x16x32_bf16(al[i], bh[j], acc[i][j], 0, 0, 0);
  }

  #pragma unroll
  for (int i = 0; i < 4; ++i)
    #pragma unroll
    for (int j = 0; j < 4; ++j) {
      int col = bn + wc + 16 * j + r16;
      #pragma unroll
      for (int r = 0; r < 4; ++r) {
        int row = bm + wr + 16 * i + kg * 4 + r;
        C[(size_t)row * N + col] = acc[i][j][r];
      }
    }
}

// ---------------------------------------------------------------------------
// RMSNorm + RoPE on q,k of qkv[b,s,6144]; emits split-bf16 Q,K [b,h,s,d].
// ---------------------------------------------------------------------------
__global__ __launch_bounds__(256) void rmsrope_split(
    const float* __restrict__ qkv, const float* __restrict__ cosb,
    const float* __restrict__ sinb, unsigned short* __restrict__ Qh,
    unsigned short* __restrict__ Ql, unsigned short* __restrict__ Kh,
    unsigned short* __restrict__ Kl) {
  const int blk = blockIdx.x;           // b*SEQ + s
  const int b = blk >> 11, s = blk & (SEQ - 1);
  const int wave = threadIdx.x >> 6, lane = threadIdx.x & 63;
  const float* base = qkv + (size_t)blk * (3 * DIM);
  const float c  = cosb[s * HD + 2 * lane];
  const float sn = sinb[s * HD + 2 * lane];
  #pragma unroll
  for (int h = wave; h < NH; h += 4) {
    float2 q = *(const float2*)(base + h * HD + 2 * lane);
    float2 k = *(const float2*)(base + DIM + h * HD + 2 * lane);
    float ssq = q.x * q.x + q.y * q.y;
    float ssk = k.x * k.x + k.y * k.y;
    #pragma unroll
    for (int off = 32; off >= 1; off >>= 1) {
      ssq += __shfl_xor(ssq, off, 64);
      ssk += __shfl_xor(ssk, off, 64);
    }
    float rq = rsqrtf(ssq * (1.0f / HD) + EPS);
    float rk = rsqrtf(ssk * (1.0f / HD) + EPS);
    float q1 = q.x * rq, q2 = q.y * rq;
    float k1 = k.x * rk, k2 = k.y * rk;
    float qy1 = q1 * c - q2 * sn, qy2 = q1 * sn + q2 * c;
    float ky1 = k1 * c - k2 * sn, ky2 = k1 * sn + k2 * c;
    size_t o = ((size_t)(b * NH + h) * SEQ + s) * HD + 2 * lane;
    ushort2 qh2, ql2, kh2, kl2;
    qh2.x = f2bf(qy1); ql2.x = f2bf(qy1 - bf2f(qh2.x));
    qh2.y = f2bf(qy2); ql2.y = f2bf(qy2 - bf2f(qh2.y));
    kh2.x = f2bf(ky1); kl2.x = f2bf(ky1 - bf2f(kh2.x));
    kh2.y = f2bf(ky2); kl2.y = f2bf(ky2 - bf2f(kh2.y));
    *(ushort2*)(Qh + o) = qh2;
    *(ushort2*)(Ql + o) = ql2;
    *(ushort2*)(Kh + o) = kh2;
    *(ushort2*)(Kl + o) = kl2;
  }
}

// ---------------------------------------------------------------------------
// V transpose+split (verified round 3)
// ---------------------------------------------------------------------------
__global__ __launch_bounds__(256) void vtrans(
    const float* __restrict__ qkv, unsigned short* __restrict__ Vth,
    unsigned short* __restrict__ Vtl) {
  __shared__ unsigned short Lh[64 * 132];
  __shared__ unsigned short Ll[64 * 132];
  const int t = threadIdx.x;
  const int s0 = blockIdx.x * 64, h = blockIdx.y, b = blockIdx.z;
  const float* src = qkv + ((size_t)(b * SEQ + s0)) * (3 * DIM) + 2 * DIM + h * HD;
  #pragma unroll
  for (int it = 0; it < 8; ++it) {
    int f = t + it * 256;
    int r = f >> 5, c4 = f & 31;
    float4 v = *(const float4*)(src + (size_t)r * (3 * DIM) + c4 * 4);
    ushort4 hh, ll;
    hh.x = f2bf(v.x); ll.x = f2bf(v.x - bf2f(hh.x));
    hh.y = f2bf(v.y); ll.y = f2bf(v.y - bf2f(hh.y));
    hh.z = f2bf(v.z); ll.z = f2bf(v.z - bf2f(hh.z));
    hh.w = f2bf(v.w); ll.w = f2bf(v.w - bf2f(hh.w));
    *(ushort4*)(&Lh[r * 132 + c4 * 4]) = hh;
    *(ushort4*)(&Ll[r * 132 + c4 * 4]) = ll;
  }
  __syncthreads();
  const int d = t >> 1, sc = (t & 1) * 32;
  size_t dst = ((size_t)((b * NH + h) * HD + d)) * SEQ + s0 + sc;
  #pragma unroll
  for (int j = 0; j < 8; ++j) {
    ushort4 oh, ol;
    oh.x = Lh[(sc + 4 * j + 0) * 132 + d]; ol.x = Ll[(sc + 4 * j + 0) * 132 + d];
    oh.y = Lh[(sc + 4 * j + 1) * 132 + d]; ol.y = Ll[(sc + 4 * j + 1) * 132 + d];
    oh.z = Lh[(sc + 4 * j + 2) * 132 + d]; ol.z = Ll[(sc + 4 * j + 2) * 132 + d];
    oh.w = Lh[(sc + 4 * j + 3) * 132 + d]; ol.w = Ll[(sc + 4 * j + 3) * 132 + d];
    *(ushort4*)(Vth + dst + j * 4) = oh;
    *(ushort4*)(Vtl + dst + j * 4) = ol;
  }
}

// ---------------------------------------------------------------------------
// MFMA flash attention, fixed-max softmax (round 4) + paired-row-swizzled
// V^T tiles (same [128][32] geometry as GEMM tiles -> conflict-free PV
// fragment reads; old layout was 2-4-way conflicted).
// ---------------------------------------------------------------------------
#define QT 128
#define KC 32
#define MFMA_B16 __builtin_amdgcn_mfma_f32_16x16x32_bf16

__global__ __launch_bounds__(256, 2) void flash_mfma(
    const unsigned short* __restrict__ Qh_g, const unsigned short* __restrict__ Ql_g,
    const unsigned short* __restrict__ Kh_g, const unsigned short* __restrict__ Kl_g,
    const unsigned short* __restrict__ Vth_g, const unsigned short* __restrict__ Vtl_g,
    unsigned short* __restrict__ Oh_g, unsigned short* __restrict__ Ol_g) {
  // [0,4096): Kh  [4096,8192): Kl  [8192,12288): Vth  [12288,16384): Vtl
  // [16384,21504): P, per wave [32][40].  Q staging reuses [0,16384).
  __shared__ __align__(16) unsigned short sm[21504];

  const int t = threadIdx.x, w = t >> 6, lane = t & 63;
  const int quad = lane >> 4, c15 = lane & 15;
  const int hy = blockIdx.y, bz = blockIdx.z;
  const int bh = bz * NH + hy;
  const int q0 = blockIdx.x * QT;
  const int wr = w * 32;

  // staging lane constants (paired-row swizzle, V tiles)
  const int srp = lane >> 3, ssl = lane & 7, sgv = ssl ^ srp;
  const int vrowc = srp * 2 + (sgv >> 2), vcolo = (sgv & 3) << 3;
  // V fragment-read lane constants
  const int rp2 = c15 >> 1;
  const int sfv = (((c15 & 1) << 2) + quad) ^ rp2;
  const int vfo = rp2 * 64 + sfv * 8;     // + nf*512 per fragment (shorts)

  // ---- load Q fragments (hi then lo) through LDS into registers ----
  bf16x8 qf[2][2][4];  // [hi/lo][mf][ks]
  const unsigned short* qsrcs[2] = {Qh_g, Ql_g};
  #pragma unroll
  for (int pass = 0; pass < 2; ++pass) {
    __syncthreads();
    const unsigned short* qsrc = qsrcs[pass] + ((size_t)bh * SEQ + q0) * HD;
    #pragma unroll
    for (int p = 0; p < 8; ++p) {
      int ci = p * 256 + t;
      int r = ci >> 4, c8 = (ci & 15) ^ (r & 15);
      __builtin_amdgcn_global_load_lds(
          (const __attribute__((address_space(1))) unsigned int*)(qsrc + (size_t)r * HD + c8 * 8),
          (__attribute__((address_space(3))) unsigned int*)(sm + ci * 8), 16, 0, 0);
    }
    __syncthreads();
    #pragma unroll
    for (int mf = 0; mf < 2; ++mf)
      #pragma unroll
      for (int ks = 0; ks < 4; ++ks) {
        int m = wr + mf * 16 + c15;
        int c8 = ks * 4 + quad;
        qf[pass][mf][ks] = *(const bf16x8*)(sm + (m * 16 + (c8 ^ (m & 15))) * 8);
      }
  }

  float lrow[8];                      // lane-local partial softmax denominators
  f32x4 oacc[2][8];
  #pragma unroll
  for (int i = 0; i < 8; ++i) lrow[i] = 0.f;
  #pragma unroll
  for (int mf = 0; mf < 2; ++mf)
    #pragma unroll
    for (int nf = 0; nf < 8; ++nf) oacc[mf][nf] = (f32x4){0.f, 0.f, 0.f, 0.f};

  const float sl = 0.12751744f;       // (1/sqrt(128)) * log2(e)
  const float M2 = 16.322231f;        // sqrt(128) * log2(e)
  unsigned short* Pw = sm + 16384 + w * 1280;

  for (int kk = 0; kk < SEQ; kk += KC) {
    __syncthreads();  // all waves done with previous K/V tiles
    if (w < 2) {      // K tiles [32][128], row-granule swizzle (verified cf)
      const unsigned short* src = (w == 0 ? Kh_g : Kl_g) + ((size_t)bh * SEQ + kk) * HD;
      #pragma unroll
      for (int p = 0; p < 8; ++p) {
        int ci = p * 64 + lane;
        int r = ci >> 4, c8 = (ci & 15) ^ (r & 15);
        __builtin_amdgcn_global_load_lds(
            (const __attribute__((address_space(1))) unsigned int*)(src + (size_t)r * HD + c8 * 8),
            (__attribute__((address_space(3))) unsigned int*)(sm + w * 4096 + ci * 8), 16, 0, 0);
      }
    } else {          // V^T tiles [128 d][32 s], paired-row swizzle
      const unsigned short* src = (w == 2 ? Vth_g : Vtl_g) + (size_t)bh * HD * SEQ + kk
                                  + (size_t)vrowc * SEQ + vcolo;
      #pragma unroll
      for (int p = 0; p < 8; ++p) {
        __builtin_amdgcn_global_load_lds(
            (const __attribute__((address_space(1))) unsigned int*)(src + (size_t)(p * 16) * SEQ),
            (__attribute__((address_space(3))) unsigned int*)(sm + w * 4096 + p * 512 + lane * 8),
            16, 0, 0);
      }
    }
    __syncthreads();

    // ---- S = Q K^T (3-pass split) ----
    f32x4 accs[2][2] = {};
    #pragma unroll
    for (int nf = 0; nf < 2; ++nf) {
      bf16x8 kh[4], kl[4];
      #pragma unroll
      for (int ks = 0; ks < 4; ++ks) {
        int n = nf * 16 + c15;
        int c8 = ks * 4 + quad;
        int slot = (n * 16 + (c8 ^ (n & 15))) * 8;
        kh[ks] = *(const bf16x8*)(sm + slot);
        kl[ks] = *(const bf16x8*)(sm + 4096 + slot);
      }
      #pragma unroll
      for (int ks = 0; ks < 4; ++ks) {
        accs[0][nf] = MFMA_B16(qf[0][0][ks], kh[ks], accs[0][nf], 0, 0, 0);
        accs[1][nf] = MFMA_B16(qf[0][1][ks], kh[ks], accs[1][nf], 0, 0, 0);
      }
      #pragma unroll
      for (int ks = 0; ks < 4; ++ks) {
        accs[0][nf] = MFMA_B16(qf[1][0][ks], kh[ks], accs[0][nf], 0, 0, 0);
        accs[1][nf] = MFMA_B16(qf[1][1][ks], kh[ks], accs[1][nf], 0, 0, 0);
        accs[0][nf] = MFMA_B16(qf[0][0][ks], kl[ks], accs[0][nf], 0, 0, 0);
        accs[1][nf] = MFMA_B16(qf[0][1][ks], kl[ks], accs[1][nf], 0, 0, 0);
      }
    }

    // ---- softmax weights with fixed shift (no reductions, no rescale) ----
    #pragma unroll
    for (int mf = 0; mf < 2; ++mf)
      #pragma unroll
      for (int reg = 0; reg < 4; ++reg) {
        float p0 = exp2f(fmaf(accs[mf][0][reg], sl, -M2));
        float p1 = exp2f(fmaf(accs[mf][1][reg], sl, -M2));
        lrow[mf * 4 + reg] += p0 + p1;
        int prow = mf * 16 + quad * 4 + reg;
        Pw[prow * 40 + c15]      = f2bf(p0);
        Pw[prow * 40 + c15 + 16] = f2bf(p1);
      }

    // ---- O += P V ----
    bf16x8 pa0 = *(const bf16x8*)(Pw + (c15) * 40 + quad * 8);
    bf16x8 pa1 = *(const bf16x8*)(Pw + (16 + c15) * 40 + quad * 8);
    #pragma unroll
    for (int nf = 0; nf < 8; ++nf) {
      bf16x8 vh = *(const bf16x8*)(sm + 8192 + nf * 512 + vfo);
      bf16x8 vl = *(const bf16x8*)(sm + 12288 + nf * 512 + vfo);
      oacc[0][nf] = MFMA_B16(pa0, vh, oacc[0][nf], 0, 0, 0);
      oacc[0][nf] = MFMA_B16(pa0, vl, oacc[0][nf], 0, 0, 0);
      oacc[1][nf] = MFMA_B16(pa1, vh, oacc[1][nf], 0, 0, 0);
      oacc[1][nf] = MFMA_B16(pa1, vl, oacc[1][nf], 0, 0, 0);
    }
  }

  // ---- epilogue ----
  #pragma unroll
  for (int i = 0; i < 8; ++i) {
    float s = lrow[i];
    #pragma unroll
    for (int off = 8; off >= 1; off >>= 1) s += __shfl_xor(s, off, 64);
    lrow[i] = s;
  }
  #pragma unroll
  for (int mf = 0; mf < 2; ++mf)
    #pragma unroll
    for (int reg = 0; reg < 4; ++reg) {
      float inv = 1.0f / lrow[mf * 4 + reg];
      int row = q0 + wr + mf * 16 + quad * 4 + reg;
      size_t ob = ((size_t)bz * SEQ + row) * DIM + hy * HD + c15;
      #pragma unroll
      for (int nf = 0; nf < 8; ++nf) {
        float val = oacc[mf][nf][reg] * inv;
        unsigned short hh = f2bf(val);
        Oh_g[ob + nf * 16] = hh;
        Ol_g[ob + nf * 16] = f2bf(val - bf2f(hh));
      }
    }
}

// ---------------------------------------------------------------------------
// Launch.  Workspace 201,326,592 B:
//   [0, 100663296)            qkv fp32  -> later Oh/Ol + Wproj split
//   [100663296, 201326592) R: xh/xl/Wh/Wl (pre-gemm1) -> Qh/Ql/Kh/Kl/Vth/Vtl
// ---------------------------------------------------------------------------
extern "C" void kernel_launch(void* const* d_in, const int* in_sizes, int n_in,
                              void* d_out, int out_size, void* d_ws, size_t ws_size,
                              hipStream_t stream) {
  const float* x     = (const float*)d_in[0];
  const float* cosb  = (const float*)d_in[1];
  const float* sinb  = (const float*)d_in[2];
  const float* Wqkv  = (const float*)d_in[3];
  const float* Wproj = (const float*)d_in[4];
  float* out = (float*)d_out;

  char* ws = (char*)d_ws;
  float* qkv = (float*)ws;
  char* R = ws + 100663296;
  unsigned short* xh = (unsigned short*)(R);
  unsigned short* xl = (unsigned short*)(R + 16777216);
  unsigned short* Wh = (unsigned short*)(R + 33554432);
  unsigned short* Wl = (unsigned short*)(R + 58720256);
  unsigned short* Qh  = (unsigned short*)(R);
  unsigned short* Ql  = (unsigned short*)(R + 16777216);
  unsigned short* Kh  = (unsigned short*)(R + 33554432);
  unsigned short* Kl  = (unsigned short*)(R + 50331648);
  unsigned short* Vth = (unsigned short*)(R + 67108864);
  unsigned short* Vtl = (unsigned short*)(R + 83886080);
  unsigned short* Oh  = (unsigned short*)(ws);
  unsigned short* Ol  = (unsigned short*)(ws + 16777216);
  unsigned short* Wph = (unsigned short*)(ws + 33554432);
  unsigned short* Wpl = (unsigned short*)(ws + 41943040);

  split_bf16<<<8192,  256, 0, stream>>>(x,    xh, xl);
  split_bf16<<<12288, 256, 0, stream>>>(Wqkv, Wh, Wl);
  gemm_split<<<dim3(48, 32), 256, 0, stream>>>(xh, xl, Wh, Wl, qkv, 4096, 6144, 2048);
  rmsrope_split<<<4096, 256, 0, stream>>>(qkv, cosb, sinb, Qh, Ql, Kh, Kl);
  vtrans<<<dim3(32, NH, BATCH), 256, 0, stream>>>(qkv, Vth, Vtl);
  flash_mfma<<<dim3(SEQ / QT, NH, BATCH), 256, 0, stream>>>(Qh, Ql, Kh, Kl, Vth, Vtl, Oh, Ol);
  split_bf16<<<4096, 256, 0, stream>>>(Wproj, Wph, Wpl);
  gemm_split<<<dim3(16, 32), 256, 0, stream>>>(Oh, Ol, Wph, Wpl, out, 4096, 2048, 2048);
}

// Round 6
// 618.448 us; speedup vs baseline: 1.2294x; 1.2294x over previous
//
#include <hip/hip_runtime.h>
#include <math.h>

// Problem constants
#define BATCH 2
#define SEQ   2048
#define DIM   2048
#define NH    16
#define HD    128
#define EPS   1e-6f

typedef _Float16 f16x8 __attribute__((ext_vector_type(8)));
typedef _Float16 f16x4 __attribute__((ext_vector_type(4)));
typedef _Float16 f16x2 __attribute__((ext_vector_type(2)));
typedef float    f32x4 __attribute__((ext_vector_type(4)));

#define MFMA_F16 __builtin_amdgcn_mfma_f32_16x16x32_f16

// W pre-scale: W*1024 keeps W_lo (~2^-12 * 0.02) in fp16 normal range.
#define WSCALE    1024.0f
#define INV_WSCALE 0.0009765625f

// ---------------------------------------------------------------------------
// fp32 -> fp16 (single), 4 el/thread
// ---------------------------------------------------------------------------
__global__ __launch_bounds__(256) void cvt_f16(
    const float* __restrict__ in, _Float16* __restrict__ out) {
  int i = blockIdx.x * 256 + threadIdx.x;
  float4 v = ((const float4*)in)[i];
  f16x4 o;
  o[0] = (_Float16)v.x; o[1] = (_Float16)v.y;
  o[2] = (_Float16)v.z; o[3] = (_Float16)v.w;
  ((f16x4*)out)[i] = o;
}

// ---------------------------------------------------------------------------
// fp32 -> (hi, lo) fp16 of value*1024 (weights)
// ---------------------------------------------------------------------------
__global__ __launch_bounds__(256) void split_f16s(
    const float* __restrict__ in, _Float16* __restrict__ hi,
    _Float16* __restrict__ lo) {
  int i = blockIdx.x * 256 + threadIdx.x;
  float4 v = ((const float4*)in)[i];
  f16x4 h, l;
  float s;
  s = v.x * WSCALE; h[0] = (_Float16)s; l[0] = (_Float16)(s - (float)h[0]);
  s = v.y * WSCALE; h[1] = (_Float16)s; l[1] = (_Float16)(s - (float)h[1]);
  s = v.z * WSCALE; h[2] = (_Float16)s; l[2] = (_Float16)(s - (float)h[2]);
  s = v.w * WSCALE; h[3] = (_Float16)s; l[3] = (_Float16)(s - (float)h[3]);
  ((f16x4*)hi)[i] = h;
  ((f16x4*)lo)[i] = l;
}

// ---------------------------------------------------------------------------
// 2-pass fp16 MFMA GEMM:  C[M,N] = A_f16[M,K] @ (Bh+Bl)[N,K]^T * outscale
// A single fp16 (its lo term dropped: 2^-12 relative).  128x128 tile, BK=32,
// 3 LDS tiles (24 KB), 24 staging chunks spread 6-per-wave, 12 ds_read_b128
// -> 32 MFMA per K-step.  Round-4 addressing (4-way frag-read conflicts
// measured non-binding; swizzle measured -3.5%).
// ---------------------------------------------------------------------------
#define BM 128
#define BN 128
#define BK 32

__global__ __launch_bounds__(256) void gemm_2p(
    const _Float16* __restrict__ Ag, const _Float16* __restrict__ Bhg,
    const _Float16* __restrict__ Blg, float* __restrict__ C,
    int M, int N, int K, float outscale) {
  __shared__ __align__(16) _Float16 As[BM * BK];
  __shared__ __align__(16) _Float16 Bhs[BM * BK];
  __shared__ __align__(16) _Float16 Bls[BM * BK];

  const int t = threadIdx.x;
  const int w = t >> 6, lane = t & 63;
  const int bm = blockIdx.y * BM, bn = blockIdx.x * BN;
  const int wr = (w >> 1) * 64, wc = (w & 1) * 64;
  const int r16 = lane & 15, kg = lane >> 4;
  const int srow = lane >> 2, scol = (lane & 3) << 3;

  const _Float16* baseA  = Ag  + (size_t)bm * K;
  const _Float16* baseBh = Bhg + (size_t)bn * K;
  const _Float16* baseBl = Blg + (size_t)bn * K;

  f32x4 acc[4][4] = {};

  for (int k0 = 0; k0 < K; k0 += BK) {
    __syncthreads();
    #pragma unroll
    for (int c = 0; c < 6; ++c) {
      int ch = w * 6 + c;            // wave-uniform
      int tile = ch >> 3, p = ch & 7;
      const _Float16* gs = (tile == 0) ? baseA : (tile == 1) ? baseBh : baseBl;
      _Float16* lb = (tile == 0) ? As : (tile == 1) ? Bhs : Bls;
      __builtin_amdgcn_global_load_lds(
          (const __attribute__((address_space(1))) unsigned int*)
              (gs + (size_t)(p * 16 + srow) * K + k0 + scol),
          (__attribute__((address_space(3))) unsigned int*)(lb + p * 512),
          16, 0, 0);
    }
    __syncthreads();

    f16x8 a[4], bh[4], bl[4];
    #pragma unroll
    for (int i = 0; i < 4; ++i) {
      a[i]  = *(const f16x8*)(As  + (wr + 16 * i + r16) * BK + kg * 8);
      bh[i] = *(const f16x8*)(Bhs + (wc + 16 * i + r16) * BK + kg * 8);
      bl[i] = *(const f16x8*)(Bls + (wc + 16 * i + r16) * BK + kg * 8);
    }
    #pragma unroll
    for (int i = 0; i < 4; ++i)
      #pragma unroll
      for (int j = 0; j < 4; ++j)
        acc[i][j] = MFMA_F16(a[i], bh[j], acc[i][j], 0, 0, 0);
    #pragma unroll
    for (int i = 0; i < 4; ++i)
      #pragma unroll
      for (int j = 0; j < 4; ++j)
        acc[i][j] = MFMA_F16(a[i], bl[j], acc[i][j], 0, 0, 0);
  }

  // C/D layout: col = lane&15, row = (lane>>4)*4 + reg
  #pragma unroll
  for (int i = 0; i < 4; ++i)
    #pragma unroll
    for (int j = 0; j < 4; ++j) {
      int col = bn + wc + 16 * j + r16;
      #pragma unroll
      for (int r = 0; r < 4; ++r) {
        int row = bm + wr + 16 * i + kg * 4 + r;
        C[(size_t)row * N + col] = acc[i][j][r] * outscale;
      }
    }
}

// ---------------------------------------------------------------------------
// RMSNorm + RoPE on q,k of qkv[b,s,6144]; emits Q fp16 (single) and K hi/lo
// fp16, layout [b,h,s,d].
// ---------------------------------------------------------------------------
__global__ __launch_bounds__(256) void rmsrope_f16(
    const float* __restrict__ qkv, const float* __restrict__ cosb,
    const float* __restrict__ sinb, _Float16* __restrict__ Qg,
    _Float16* __restrict__ Khg, _Float16* __restrict__ Klg) {
  const int blk = blockIdx.x;           // b*SEQ + s
  const int b = blk >> 11, s = blk & (SEQ - 1);
  const int wave = threadIdx.x >> 6, lane = threadIdx.x & 63;
  const float* base = qkv + (size_t)blk * (3 * DIM);
  const float c  = cosb[s * HD + 2 * lane];
  const float sn = sinb[s * HD + 2 * lane];
  #pragma unroll
  for (int h = wave; h < NH; h += 4) {
    float2 q = *(const float2*)(base + h * HD + 2 * lane);
    float2 k = *(const float2*)(base + DIM + h * HD + 2 * lane);
    float ssq = q.x * q.x + q.y * q.y;
    float ssk = k.x * k.x + k.y * k.y;
    #pragma unroll
    for (int off = 32; off >= 1; off >>= 1) {
      ssq += __shfl_xor(ssq, off, 64);
      ssk += __shfl_xor(ssk, off, 64);
    }
    float rq = rsqrtf(ssq * (1.0f / HD) + EPS);
    float rk = rsqrtf(ssk * (1.0f / HD) + EPS);
    float q1 = q.x * rq, q2 = q.y * rq;
    float k1 = k.x * rk, k2 = k.y * rk;
    float qy1 = q1 * c - q2 * sn, qy2 = q1 * sn + q2 * c;
    float ky1 = k1 * c - k2 * sn, ky2 = k1 * sn + k2 * c;
    size_t o = ((size_t)(b * NH + h) * SEQ + s) * HD + 2 * lane;
    f16x2 qo, kh, kl;
    qo[0] = (_Float16)qy1; qo[1] = (_Float16)qy2;
    kh[0] = (_Float16)ky1; kl[0] = (_Float16)(ky1 - (float)kh[0]);
    kh[1] = (_Float16)ky2; kl[1] = (_Float16)(ky2 - (float)kh[1]);
    *(f16x2*)(Qg  + o) = qo;
    *(f16x2*)(Khg + o) = kh;
    *(f16x2*)(Klg + o) = kl;
  }
}

// ---------------------------------------------------------------------------
// V transpose: qkv v-slice [64 s][128 d] fp32 -> Vt [b,h,d,s] single fp16.
// ---------------------------------------------------------------------------
__global__ __launch_bounds__(256) void vtrans_f16(
    const float* __restrict__ qkv, _Float16* __restrict__ Vt) {
  __shared__ _Float16 L[64 * 132];
  const int t = threadIdx.x;
  const int s0 = blockIdx.x * 64, h = blockIdx.y, b = blockIdx.z;
  const float* src = qkv + ((size_t)(b * SEQ + s0)) * (3 * DIM) + 2 * DIM + h * HD;
  #pragma unroll
  for (int it = 0; it < 8; ++it) {
    int f = t + it * 256;
    int r = f >> 5, c4 = f & 31;
    float4 v = *(const float4*)(src + (size_t)r * (3 * DIM) + c4 * 4);
    f16x4 o;
    o[0] = (_Float16)v.x; o[1] = (_Float16)v.y;
    o[2] = (_Float16)v.z; o[3] = (_Float16)v.w;
    *(f16x4*)(&L[r * 132 + c4 * 4]) = o;
  }
  __syncthreads();
  const int d = t >> 1, sc = (t & 1) * 32;
  size_t dst = ((size_t)((b * NH + h) * HD + d)) * SEQ + s0 + sc;
  #pragma unroll
  for (int j = 0; j < 8; ++j) {
    f16x4 o;
    o[0] = L[(sc + 4 * j + 0) * 132 + d];
    o[1] = L[(sc + 4 * j + 1) * 132 + d];
    o[2] = L[(sc + 4 * j + 2) * 132 + d];
    o[3] = L[(sc + 4 * j + 3) * 132 + d];
    *(f16x4*)(Vt + dst + j * 4) = o;
  }
}

// ---------------------------------------------------------------------------
// fp16 MFMA flash attention, fixed-max softmax.
// QK^T: Q single fp16 x (Kh + Kl) = 2 passes.  PV: P fp16 x V fp16 = 1 pass.
// 48 MFMA / K-chunk (was 80).  LDS: Kh/Kl/Vt 8 KB each + P 10 KB = 34 KB.
// ---------------------------------------------------------------------------
#define QT 128
#define KC 32

__global__ __launch_bounds__(256, 2) void flash_f16(
    const _Float16* __restrict__ Qg, const _Float16* __restrict__ Khg,
    const _Float16* __restrict__ Klg, const _Float16* __restrict__ Vtg,
    _Float16* __restrict__ Og) {
  // shorts(f16): Kh [0,4096)  Kl [4096,8192)  Vt [8192,12288)
  // P [12288,17408): per wave [32][40].  Q staging reuses [0,16384).
  __shared__ __align__(16) _Float16 sm[17408];

  const int t = threadIdx.x, w = t >> 6, lane = t & 63;
  const int quad = lane >> 4, c15 = lane & 15;
  const int hy = blockIdx.y, bz = blockIdx.z;
  const int bh = bz * NH + hy;
  const int q0 = blockIdx.x * QT;
  const int wr = w * 32;

  // ---- stage Q [128][128] f16 once; fragments -> registers ----
  {
    const _Float16* qsrc = Qg + ((size_t)bh * SEQ + q0) * HD;
    #pragma unroll
    for (int p = 0; p < 8; ++p) {
      int ci = p * 256 + t;
      int r = ci >> 4, c8 = (ci & 15) ^ (r & 15);
      __builtin_amdgcn_global_load_lds(
          (const __attribute__((address_space(1))) unsigned int*)(qsrc + (size_t)r * HD + c8 * 8),
          (__attribute__((address_space(3))) unsigned int*)(sm + ci * 8), 16, 0, 0);
    }
  }
  __syncthreads();
  f16x8 qf[2][4];  // [mf][ks]
  #pragma unroll
  for (int mf = 0; mf < 2; ++mf)
    #pragma unroll
    for (int ks = 0; ks < 4; ++ks) {
      int m = wr + mf * 16 + c15;
      int c8 = ks * 4 + quad;
      qf[mf][ks] = *(const f16x8*)(sm + (m * 16 + (c8 ^ (m & 15))) * 8);
    }

  float lrow[8];
  f32x4 oacc[2][8];
  #pragma unroll
  for (int i = 0; i < 8; ++i) lrow[i] = 0.f;
  #pragma unroll
  for (int mf = 0; mf < 2; ++mf)
    #pragma unroll
    for (int nf = 0; nf < 8; ++nf) oacc[mf][nf] = (f32x4){0.f, 0.f, 0.f, 0.f};

  const float sl = 0.12751744f;       // (1/sqrt(128)) * log2(e)
  const float M2 = 16.322231f;        // sqrt(128) * log2(e)  (|score|<=sqrt(128))
  _Float16* Pw = sm + 12288 + w * 1280;

  for (int kk = 0; kk < SEQ; kk += KC) {
    __syncthreads();  // all waves done with previous tiles (and Q frags at kk=0)
    if (w == 0 || w == 1) {   // Kh / Kl tiles [32][128]
      const _Float16* src = (w == 0 ? Khg : Klg) + ((size_t)bh * SEQ + kk) * HD;
      #pragma unroll
      for (int p = 0; p < 8; ++p) {
        int ci = p * 64 + lane;
        int r = ci >> 4, c8 = (ci & 15) ^ (r & 15);
        __builtin_amdgcn_global_load_lds(
            (const __attribute__((address_space(1))) unsigned int*)(src + (size_t)r * HD + c8 * 8),
            (__attribute__((address_space(3))) unsigned int*)(sm + w * 4096 + ci * 8), 16, 0, 0);
      }
    } else if (w == 2) {      // V^T tile [128 d][32 s]
      const _Float16* src = Vtg + (size_t)bh * HD * SEQ + kk;
      #pragma unroll
      for (int p = 0; p < 8; ++p) {
        int ci = p * 64 + lane;
        int d = ci >> 2, c8 = (ci & 3) ^ (d & 3);
        __builtin_amdgcn_global_load_lds(
            (const __attribute__((address_space(1))) unsigned int*)(src + (size_t)d * SEQ + c8 * 8),
            (__attribute__((address_space(3))) unsigned int*)(sm + 8192 + ci * 8), 16, 0, 0);
      }
    }
    __syncthreads();

    // ---- S = Q K^T (2 passes: Kh then Kl) ----
    f32x4 accs[2][2] = {};
    #pragma unroll
    for (int nf = 0; nf < 2; ++nf) {
      f16x8 kh[4], kl[4];
      #pragma unroll
      for (int ks = 0; ks < 4; ++ks) {
        int n = nf * 16 + c15;
        int c8 = ks * 4 + quad;
        int slot = (n * 16 + (c8 ^ (n & 15))) * 8;
        kh[ks] = *(const f16x8*)(sm + slot);
        kl[ks] = *(const f16x8*)(sm + 4096 + slot);
      }
      #pragma unroll
      for (int ks = 0; ks < 4; ++ks) {
        accs[0][nf] = MFMA_F16(qf[0][ks], kh[ks], accs[0][nf], 0, 0, 0);
        accs[1][nf] = MFMA_F16(qf[1][ks], kh[ks], accs[1][nf], 0, 0, 0);
      }
      #pragma unroll
      for (int ks = 0; ks < 4; ++ks) {
        accs[0][nf] = MFMA_F16(qf[0][ks], kl[ks], accs[0][nf], 0, 0, 0);
        accs[1][nf] = MFMA_F16(qf[1][ks], kl[ks], accs[1][nf], 0, 0, 0);
      }
    }

    // ---- fixed-shift softmax weights (lane-local denominator) ----
    #pragma unroll
    for (int mf = 0; mf < 2; ++mf)
      #pragma unroll
      for (int reg = 0; reg < 4; ++reg) {
        float p0 = exp2f(fmaf(accs[mf][0][reg], sl, -M2));
        float p1 = exp2f(fmaf(accs[mf][1][reg], sl, -M2));
        lrow[mf * 4 + reg] += p0 + p1;
        int prow = mf * 16 + quad * 4 + reg;
        Pw[prow * 40 + c15]      = (_Float16)p0;
        Pw[prow * 40 + c15 + 16] = (_Float16)p1;
      }

    // ---- O += P V (single pass) ----
    f16x8 pa0 = *(const f16x8*)(Pw + (c15) * 40 + quad * 8);
    f16x8 pa1 = *(const f16x8*)(Pw + (16 + c15) * 40 + quad * 8);
    #pragma unroll
    for (int nf = 0; nf < 8; ++nf) {
      int dd = nf * 16 + c15;
      int slot = (dd * 4 + (quad ^ (dd & 3))) * 8;
      f16x8 vv = *(const f16x8*)(sm + 8192 + slot);
      oacc[0][nf] = MFMA_F16(pa0, vv, oacc[0][nf], 0, 0, 0);
      oacc[1][nf] = MFMA_F16(pa1, vv, oacc[1][nf], 0, 0, 0);
    }
  }

  // ---- epilogue: denominator reduce + O write (single fp16) ----
  #pragma unroll
  for (int i = 0; i < 8; ++i) {
    float s = lrow[i];
    #pragma unroll
    for (int off = 8; off >= 1; off >>= 1) s += __shfl_xor(s, off, 64);
    lrow[i] = s;
  }
  #pragma unroll
  for (int mf = 0; mf < 2; ++mf)
    #pragma unroll
    for (int reg = 0; reg < 4; ++reg) {
      float inv = 1.0f / lrow[mf * 4 + reg];
      int row = q0 + wr + mf * 16 + quad * 4 + reg;
      size_t ob = ((size_t)bz * SEQ + row) * DIM + hy * HD + c15;
      #pragma unroll
      for (int nf = 0; nf < 8; ++nf)
        Og[ob + nf * 16] = (_Float16)(oacc[mf][nf][reg] * inv);
    }
}

// ---------------------------------------------------------------------------
// Launch.  Workspace (<= 201 MB):
//   [0, 100663296)          qkv fp32 -> later O16 + Wph/Wpl
//   R = +100663296:
//     pre-gemm1 : x16 [R,+16.7M)  Wh [R+16.7M,+25.2M)  Wl [R+41.9M,+25.2M)
//     post-gemm1: Q16 [R) Kh [R+16.7M) Kl [R+33.6M) Vt [R+50.3M) (16.7M each)
//   O16 at ws[0,16.7M), Wph ws+16.7M, Wpl ws+25.2M (after qkv consumed).
// ---------------------------------------------------------------------------
extern "C" void kernel_launch(void* const* d_in, const int* in_sizes, int n_in,
                              void* d_out, int out_size, void* d_ws, size_t ws_size,
                              hipStream_t stream) {
  const float* x     = (const float*)d_in[0];
  const float* cosb  = (const float*)d_in[1];
  const float* sinb  = (const float*)d_in[2];
  const float* Wqkv  = (const float*)d_in[3];
  const float* Wproj = (const float*)d_in[4];
  float* out = (float*)d_out;

  char* ws = (char*)d_ws;
  float* qkv = (float*)ws;
  char* R = ws + 100663296;
  _Float16* x16 = (_Float16*)(R);
  _Float16* Wh  = (_Float16*)(R + 16777216);
  _Float16* Wl  = (_Float16*)(R + 41943040);
  _Float16* Q16 = (_Float16*)(R);
  _Float16* Kh  = (_Float16*)(R + 16777216);
  _Float16* Kl  = (_Float16*)(R + 33554432);
  _Float16* Vt  = (_Float16*)(R + 50331648);
  _Float16* O16 = (_Float16*)(ws);
  _Float16* Wph = (_Float16*)(ws + 16777216);
  _Float16* Wpl = (_Float16*)(ws + 25165824);

  cvt_f16  <<<8192,  256, 0, stream>>>(x, x16);
  split_f16s<<<12288, 256, 0, stream>>>(Wqkv, Wh, Wl);
  gemm_2p<<<dim3(48, 32), 256, 0, stream>>>(x16, Wh, Wl, qkv, 4096, 6144, 2048, INV_WSCALE);
  rmsrope_f16<<<4096, 256, 0, stream>>>(qkv, cosb, sinb, Q16, Kh, Kl);
  vtrans_f16<<<dim3(32, NH, BATCH), 256, 0, stream>>>(qkv, Vt);
  split_f16s<<<4096, 256, 0, stream>>>(Wproj, Wph, Wpl);   // after qkv consumed
  flash_f16<<<dim3(SEQ / QT, NH, BATCH), 256, 0, stream>>>(Q16, Kh, Kl, Vt, O16);
  gemm_2p<<<dim3(16, 32), 256, 0, stream>>>(O16, Wph, Wpl, out, 4096, 2048, 2048, INV_WSCALE);
}